// Round 22
// baseline (192.884 us; speedup 1.0000x reference)
//
#include <hip/hip_runtime.h>
#include <hip/hip_bf16.h>
#include <stdint.h>

#define QL   2048
#define KLn  2048
#define DIM  512
#define NH   8
#define DH   64
#define NB   2
#define MROWS (NB*QL)   // 4096
#define FFD  2048

typedef unsigned short u16;
typedef unsigned int u32;
typedef __attribute__((ext_vector_type(8))) short short8;
typedef __attribute__((ext_vector_type(4))) float f32x4;

__device__ __forceinline__ u16 f2b(float f){
  union { float f; u32 i; } v; v.f = f;
  u32 r = v.i + 0x7FFFu + ((v.i >> 16) & 1u);
  return (u16)(r >> 16);
}
__device__ __forceinline__ float b2f(u16 u){
  union { u32 i; float f; } v; v.i = ((u32)u) << 16; return v.f;
}
// two f32 -> packed bf16x2 in one instruction (lo=a, hi=b, RNE)
__device__ __forceinline__ u32 cvtpk(float a, float b){
  u32 r;
  asm("v_cvt_pk_bf16_f32 %0, %1, %2" : "=v"(r) : "v"(a), "v"(b));
  return r;
}

typedef __attribute__((address_space(3))) void as3void;
typedef __attribute__((address_space(1))) void as1void;
__device__ __forceinline__ void gload_lds16(const void* g, void* l){
  __builtin_amdgcn_global_load_lds((as1void*)g, (as3void*)l, 16, 0, 0);
}

// ---------------------------------------------------------------- GEMM (64x64)
#define BK 64
enum { EPI_BIAS=0, EPI_SCALEQ=1, EPI_RELU=2, EPI_RES=3, EPI_FIN=5, EPI_QKV=6, EPI_KV=7 };
// 1/sqrt(64) * log2(e): folds softmax exp->exp2 conversion into Q scale
#define QSCALE 0.1803368801111244f

template<int EPI>
__global__ __launch_bounds__(256, 4)
void gemm64(const u16* __restrict__ A, const u16* __restrict__ Bt,
            const float* __restrict__ bias,
            u16* __restrict__ Obf, float* __restrict__ Ores,
            const float* __restrict__ tk, float* __restrict__ fout,
            int K, int N)
{
  __shared__ __align__(16) u16 As[2][64*BK];
  __shared__ __align__(16) u16 Bs[2][64*BK];
  const int t  = threadIdx.x;
  const int l  = t & 63;
  const int lq = l & 15, lg = l >> 4;
  const int w  = t >> 6;
  const int wm = (w >> 1) * 32;
  const int wn = (w & 1) * 32;

  const int gx   = gridDim.x;
  const int nwg  = gx * gridDim.y;
  const int orig = blockIdx.x + gx * blockIdx.y;
  const int wgid = (orig & 7) * (nwg >> 3) + (orig >> 3);
  const int m0 = (wgid / gx) * 64;
  const int n0 = (wgid % gx) * 64;

  const int srow = t >> 3;   // 0..31
  const int scs  = t & 7;

  auto stageG = [&](u16* dA, u16* dB, int k0){
    _Pragma("unroll")
    for (int i = 0; i < 2; ++i){
      const int row = i*32 + srow;
      gload_lds16(A  + (size_t)(m0 + row)*K + k0 + ((scs ^ (row & 7)) << 3),
                  dA + row*BK + scs*8);
      gload_lds16(Bt + (size_t)(n0 + row)*K + k0 + ((scs ^ (row & 7)) << 3),
                  dB + row*BK + scs*8);
    }
  };

  int aoff[2][2], boff[2][2];
  _Pragma("unroll")
  for (int i = 0; i < 2; ++i)
    _Pragma("unroll")
    for (int kc = 0; kc < 2; ++kc){
      const int sw = (((kc*4 + lg) ^ (lq & 7)) << 3);
      aoff[i][kc] = ((wm + i*16 + lq)*BK + sw) * 2;
      boff[i][kc] = ((wn + i*16 + lq)*BK + sw) * 2;
    }

  f32x4 acc[2][2];
  _Pragma("unroll")
  for (int i=0;i<2;i++)
    _Pragma("unroll")
    for (int j=0;j<2;j++) acc[i][j] = (f32x4){0.f,0.f,0.f,0.f};

#define GBODY(BUF, KK)                                                        \
  {                                                                           \
    { const int ks = ((KK) + BK < K) ? (KK) + BK : 0;                         \
      stageG(As[(BUF)^1], Bs[(BUF)^1], ks); }                                 \
    asm volatile("s_waitcnt vmcnt(4)" ::: "memory");                          \
    __builtin_amdgcn_s_barrier();                                             \
    __builtin_amdgcn_sched_barrier(0);                                        \
    short8 af[2][2], bf[2][2];                                                \
    _Pragma("unroll")                                                         \
    for (int kc = 0; kc < 2; ++kc)                                            \
      _Pragma("unroll")                                                       \
      for (int i = 0; i < 2; ++i){                                            \
        af[i][kc] = *(const short8*)((const char*)As + (BUF)*8192 + aoff[i][kc]); \
        bf[i][kc] = *(const short8*)((const char*)Bs + (BUF)*8192 + boff[i][kc]); \
      }                                                                       \
    __builtin_amdgcn_s_barrier();                                             \
    __builtin_amdgcn_s_setprio(1);                                            \
    _Pragma("unroll")                                                         \
    for (int kc = 0; kc < 2; ++kc)                                            \
      _Pragma("unroll")                                                       \
      for (int i = 0; i < 2; ++i)                                             \
        _Pragma("unroll")                                                     \
        for (int j = 0; j < 2; ++j)                                           \
          acc[i][j] = __builtin_amdgcn_mfma_f32_16x16x32_bf16(af[i][kc], bf[j][kc], acc[i][j], 0,0,0); \
    __builtin_amdgcn_s_setprio(0);                                            \
  }

  stageG(As[0], Bs[0], 0);
  for (int k0 = 0; k0 < K; k0 += 2*BK){
    GBODY(0, k0)
    GBODY(1, k0 + BK)
  }
#undef GBODY

  _Pragma("unroll")
  for (int i=0;i<2;i++){
    _Pragma("unroll")
    for (int j=0;j<2;j++){
      _Pragma("unroll")
      for (int rr=0;rr<4;rr++){
        const int row = m0 + wm + i*16 + lg*4 + rr;
        const int col = n0 + wn + j*16 + lq;
        float v = acc[i][j][rr] + bias[col];
        if (EPI == EPI_SCALEQ) v *= QSCALE;
        if (EPI == EPI_RELU)   v = fmaxf(v, 0.f);
        if (EPI == EPI_RES)    Ores[(size_t)row*N + col] += v;
        else if (EPI == EPI_FIN){
          const size_t idx = (size_t)row*N + col;
          fout[idx] = (Ores[idx] + v) * tk[row];
        }
        else if (EPI == EPI_QKV){
          const int seg = col >> 9, c = col & 511;
          if (seg == 0)      Obf[(size_t)row*512 + c] = f2b(v * QSCALE);
          else if (seg == 1){
            const int bb = row >> 11, kv = row & 2047;
            const int hh = c >> 6,  dh = c & 63;
            Obf[(2u<<20) + ((((size_t)(bb*NH + hh) << 11) + kv) << 6) + (dh ^ ((kv & 7) << 3))] = f2b(v);
          }
          else               Obf[(4u<<20) + (size_t)row*512 + c] = f2b(v);
        }
        else if (EPI == EPI_KV){
          const int seg = col >> 9, c = col & 511;
          if (seg == 0){
            const int bb = row >> 11, kv = row & 2047;
            const int hh = c >> 6,  dh = c & 63;
            Obf[((((size_t)(bb*NH + hh) << 11) + kv) << 6) + (dh ^ ((kv & 7) << 3))] = f2b(v);
          }
          else               Obf[(2u<<20) + (size_t)row*512 + c] = f2b(v);
        }
        else                   Obf[(size_t)row*N + col] = f2b(v);
      }
    }
  }
}

// ---------------------------------------------------------------- cross-QKV
// Fused launch of the two INDEPENDENT cross-attn projections.
__global__ __launch_bounds__(256, 4)
void gemm_cross(const u16* __restrict__ t2n_, const u16* __restrict__ memb_,
                const u16* __restrict__ BtQ, const u16* __restrict__ BtKV,
                const float* __restrict__ biasQ, const float* __restrict__ biasKV,
                u16* __restrict__ qb_, u16* __restrict__ kb_)
{
  const int K = 512;
  __shared__ __align__(16) u16 As[2][64*BK];
  __shared__ __align__(16) u16 Bs[2][64*BK];
  const int t  = threadIdx.x;
  const int l  = t & 63;
  const int lq = l & 15, lg = l >> 4;
  const int w  = t >> 6;
  const int wm = (w >> 1) * 32;
  const int wn = (w & 1) * 32;

  const int gx   = gridDim.x;                 // 24
  const int nwg  = gx * gridDim.y;            // 1536
  const int orig = blockIdx.x + gx * blockIdx.y;
  const int wgid = (orig & 7) * (nwg >> 3) + (orig >> 3);
  const int part = (wgid < 512) ? 0 : 1;
  const int id   = part ? wgid - 512 : wgid;
  const int gxp  = part ? 16 : 8;
  const int m0 = (id / gxp) * 64;
  const int n0 = (id % gxp) * 64;

  const u16* A   = part ? memb_ : t2n_;
  const u16* Bt  = part ? BtKV  : BtQ;
  const float* bias = part ? biasKV : biasQ;

  const int srow = t >> 3;
  const int scs  = t & 7;

  auto stageG = [&](u16* dA, u16* dB, int k0){
    _Pragma("unroll")
    for (int i = 0; i < 2; ++i){
      const int row = i*32 + srow;
      gload_lds16(A  + (size_t)(m0 + row)*K + k0 + ((scs ^ (row & 7)) << 3),
                  dA + row*BK + scs*8);
      gload_lds16(Bt + (size_t)(n0 + row)*K + k0 + ((scs ^ (row & 7)) << 3),
                  dB + row*BK + scs*8);
    }
  };

  int aoff[2][2], boff[2][2];
  _Pragma("unroll")
  for (int i = 0; i < 2; ++i)
    _Pragma("unroll")
    for (int kc = 0; kc < 2; ++kc){
      const int sw = (((kc*4 + lg) ^ (lq & 7)) << 3);
      aoff[i][kc] = ((wm + i*16 + lq)*BK + sw) * 2;
      boff[i][kc] = ((wn + i*16 + lq)*BK + sw) * 2;
    }

  f32x4 acc[2][2];
  _Pragma("unroll")
  for (int i=0;i<2;i++)
    _Pragma("unroll")
    for (int j=0;j<2;j++) acc[i][j] = (f32x4){0.f,0.f,0.f,0.f};

#define GBODY(BUF, KK)                                                        \
  {                                                                           \
    { const int ks = ((KK) + BK < K) ? (KK) + BK : 0;                         \
      stageG(As[(BUF)^1], Bs[(BUF)^1], ks); }                                 \
    asm volatile("s_waitcnt vmcnt(4)" ::: "memory");                          \
    __builtin_amdgcn_s_barrier();                                             \
    __builtin_amdgcn_sched_barrier(0);                                        \
    short8 af[2][2], bf[2][2];                                                \
    _Pragma("unroll")                                                         \
    for (int kc = 0; kc < 2; ++kc)                                            \
      _Pragma("unroll")                                                       \
      for (int i = 0; i < 2; ++i){                                            \
        af[i][kc] = *(const short8*)((const char*)As + (BUF)*8192 + aoff[i][kc]); \
        bf[i][kc] = *(const short8*)((const char*)Bs + (BUF)*8192 + boff[i][kc]); \
      }                                                                       \
    __builtin_amdgcn_s_barrier();                                             \
    __builtin_amdgcn_s_setprio(1);                                            \
    _Pragma("unroll")                                                         \
    for (int kc = 0; kc < 2; ++kc)                                            \
      _Pragma("unroll")                                                       \
      for (int i = 0; i < 2; ++i)                                             \
        _Pragma("unroll")                                                     \
        for (int j = 0; j < 2; ++j)                                           \
          acc[i][j] = __builtin_amdgcn_mfma_f32_16x16x32_bf16(af[i][kc], bf[j][kc], acc[i][j], 0,0,0); \
    __builtin_amdgcn_s_setprio(0);                                            \
  }

  stageG(As[0], Bs[0], 0);
  for (int k0 = 0; k0 < K; k0 += 2*BK){
    GBODY(0, k0)
    GBODY(1, k0 + BK)
  }
#undef GBODY

  _Pragma("unroll")
  for (int i=0;i<2;i++){
    _Pragma("unroll")
    for (int j=0;j<2;j++){
      _Pragma("unroll")
      for (int rr=0;rr<4;rr++){
        const int row = m0 + wm + i*16 + lg*4 + rr;
        const int col = n0 + wn + j*16 + lq;
        float v = acc[i][j][rr] + bias[col];
        if (part == 0){
          qb_[(size_t)row*512 + col] = f2b(v * QSCALE);
        } else {
          const int seg = col >> 9, c = col & 511;
          if (seg == 0){
            const int bb = row >> 11, kv = row & 2047;
            const int hh = c >> 6,  dh = c & 63;
            kb_[((((size_t)(bb*NH + hh) << 11) + kv) << 6) + (dh ^ ((kv & 7) << 3))] = f2b(v);
          }
          else kb_[(2u<<20) + (size_t)row*512 + c] = f2b(v);
        }
      }
    }
  }
}

// ---------------------------------------------------------------- O-proj GEMM
// with the flash-decode merge FUSED into the A-operand staging.
__global__ __launch_bounds__(256, 4)
void gemm_om(const u16* __restrict__ ctxp, const float2* __restrict__ mlb,
             const u16* __restrict__ Bt, const float* __restrict__ bias,
             float* __restrict__ Ores)
{
  const int K = 512, N = 512;
  __shared__ __align__(16) u16 As[2][64*BK];
  __shared__ __align__(16) u16 Bs[2][64*BK];
  const int t  = threadIdx.x;
  const int l  = t & 63;
  const int lq = l & 15, lg = l >> 4;
  const int w  = t >> 6;
  const int wm = (w >> 1) * 32;
  const int wn = (w & 1) * 32;

  const int gx   = gridDim.x;
  const int nwg  = gx * gridDim.y;
  const int orig = blockIdx.x + gx * blockIdx.y;
  const int wgid = (orig & 7) * (nwg >> 3) + (orig >> 3);
  const int m0 = (wgid / gx) * 64;
  const int n0 = (wgid % gx) * 64;

  const int srow = t >> 3;   // 0..31
  const int scs  = t & 7;

  typedef __attribute__((ext_vector_type(4))) u32 u32x4;
  union Apack { u32x4 v; u16 e[8]; };

  auto loadA = [&](Apack* c0, Apack* c1, float2* a0, float2* a1, int k0){
    _Pragma("unroll")
    for (int i = 0; i < 2; ++i){
      const int row  = i*32 + srow;
      const int grow = m0 + row;
      const int b_   = grow >> 11, qr = grow & 2047;
      const int kk   = k0 + ((scs ^ (row & 7)) << 3);
      const int h_   = kk >> 6;
      c0[i].v = *(const u32x4*)&ctxp[(size_t)grow*512 + kk];
      c1[i].v = *(const u32x4*)&ctxp[(size_t)MROWS*512 + (size_t)grow*512 + kk];
      a0[i] = mlb[((size_t)(b_*NH + h_) << 11) + qr];
      a1[i] = mlb[((size_t)((NB + b_)*NH + h_) << 11) + qr];
    }
  };
  auto writeA = [&](u16* dA, Apack* c0, Apack* c1, float2* a0, float2* a1){
    _Pragma("unroll")
    for (int i = 0; i < 2; ++i){
      const int row = i*32 + srow;
      const float mg = fmaxf(a0[i].x, a1[i].x);
      const float w0 = exp2f(a0[i].x - mg), w1 = exp2f(a1[i].x - mg);
      const float rd = 1.f / (a0[i].y*w0 + a1[i].y*w1);
      u32x4 o;
      _Pragma("unroll")
      for (int j = 0; j < 4; ++j)
        o[j] = cvtpk((b2f(c0[i].e[2*j  ])*w0 + b2f(c1[i].e[2*j  ])*w1) * rd,
                     (b2f(c0[i].e[2*j+1])*w0 + b2f(c1[i].e[2*j+1])*w1) * rd);
      *(u32x4*)&dA[row*BK + scs*8] = o;
    }
  };
  auto stageB = [&](u16* dB, int k0){
    _Pragma("unroll")
    for (int i = 0; i < 2; ++i){
      const int row = i*32 + srow;
      gload_lds16(Bt + (size_t)(n0 + row)*K + k0 + ((scs ^ (row & 7)) << 3),
                  dB + row*BK + scs*8);
    }
  };

  int aoff[2][2], boff[2][2];
  _Pragma("unroll")
  for (int i = 0; i < 2; ++i)
    _Pragma("unroll")
    for (int kc = 0; kc < 2; ++kc){
      const int sw = (((kc*4 + lg) ^ (lq & 7)) << 3);
      aoff[i][kc] = ((wm + i*16 + lq)*BK + sw) * 2;
      boff[i][kc] = ((wn + i*16 + lq)*BK + sw) * 2;
    }

  f32x4 acc[2][2];
  _Pragma("unroll")
  for (int i=0;i<2;i++)
    _Pragma("unroll")
    for (int j=0;j<2;j++) acc[i][j] = (f32x4){0.f,0.f,0.f,0.f};

  {
    Apack c0[2], c1[2]; float2 a0[2], a1[2];
    loadA(c0, c1, a0, a1, 0);
    stageB(Bs[0], 0);
    writeA(As[0], c0, c1, a0, a1);
  }
  int cur = 0;
  for (int k0 = 0; k0 < K; k0 += BK){
    __syncthreads();                       // A ds_writes + B gloads visible
    short8 af[2][2], bf[2][2];
    _Pragma("unroll")
    for (int kc = 0; kc < 2; ++kc)
      _Pragma("unroll")
      for (int i = 0; i < 2; ++i){
        af[i][kc] = *(const short8*)((const char*)As + cur*8192 + aoff[i][kc]);
        bf[i][kc] = *(const short8*)((const char*)Bs + cur*8192 + boff[i][kc]);
      }
    __syncthreads();                       // reads done; other buf writable
    const bool has = (k0 + BK) < K;
    Apack c0[2], c1[2]; float2 a0[2], a1[2];
    if (has){
      loadA(c0, c1, a0, a1, k0 + BK);      // loads fly under the MFMA block
      stageB(Bs[cur^1], k0 + BK);
    }
    __builtin_amdgcn_s_setprio(1);
    _Pragma("unroll")
    for (int kc = 0; kc < 2; ++kc)
      _Pragma("unroll")
      for (int i = 0; i < 2; ++i)
        _Pragma("unroll")
        for (int j = 0; j < 2; ++j)
          acc[i][j] = __builtin_amdgcn_mfma_f32_16x16x32_bf16(af[i][kc], bf[j][kc], acc[i][j], 0,0,0);
    __builtin_amdgcn_s_setprio(0);
    if (has) writeA(As[cur^1], c0, c1, a0, a1);
    cur ^= 1;
  }

  _Pragma("unroll")
  for (int i=0;i<2;i++){
    _Pragma("unroll")
    for (int j=0;j<2;j++){
      _Pragma("unroll")
      for (int rr=0;rr<4;rr++){
        const int row = m0 + wm + i*16 + lg*4 + rr;
        const int col = n0 + wn + j*16 + lq;
        Ores[(size_t)row*N + col] += acc[i][j][rr] + bias[col];
      }
    }
  }
}

// ---------------------------------------------------------------- attention v8d
// = v8c + XCD-aware block remap (T1): all 16 q-tiles sharing one (h,b,half)
// K/V working set (256 KB) land on ONE XCD -> K/V becomes L2-resident after
// the first touch (R21 evidence: FETCH 37MB vs 16MB unique = 3x HBM re-fetch
// because default order round-robins same-K/V blocks across all 8 XCDs).
// Bijective: orig in [0,512); xcd=orig&7, slot=orig>>3; grp=xcd+8*(slot>>4);
// qtile=slot&15; h=grp&7; z=grp>>3.
template<bool CAUSAL>
__global__ __launch_bounds__(256, 2)
void attn8(const u16* __restrict__ Q, const u16* __restrict__ Kbh,
           const u16* __restrict__ Vth, const float* __restrict__ bias,
           u16* __restrict__ ctxp, float2* __restrict__ mlb)
{
  __shared__ __align__(16) u16 Kl[4][64*64];   // 32 KB
  __shared__ __align__(16) u16 Vl[4][64*64];   // 32 KB
  const int tid = threadIdx.x;
  const int l  = tid & 63;
  const int w  = tid >> 6;
  const int lq = l & 15, lg = l >> 4;

  // XCD-aware remap (grid is (16, 8, 4); HW round-robins linear id % 8 -> XCD)
  const int orig = (int)blockIdx.x + 16*((int)blockIdx.y + 8*(int)blockIdx.z);
  const int xcd  = orig & 7, slot = orig >> 3;
  const int grp  = xcd + 8*(slot >> 4);        // 0..31
  const int qtile = slot & 15;
  const int h    = grp & 7;
  const int z    = grp >> 3;                   // 0..3
  const int b    = z >> 1;
  const int half = z & 1;
  const int rw = qtile*128 + w*32;             // wave's first q-row

  const u16* kg = Kbh + ((size_t)(b*NH + h) << 17);   // [2048][64]
  const u16* vg = Vth + ((size_t)(b*NH + h) << 17);   // [64][2048]

  short8 aq[2][2];
  _Pragma("unroll")
  for (int g = 0; g < 2; ++g)
    _Pragma("unroll")
    for (int kc = 0; kc < 2; ++kc)
      aq[g][kc] = *(const short8*)(Q + (size_t)(b*QL + rw + g*16 + lq)*DIM + h*DH + kc*32 + lg*8);

  int koff[4][2];
  _Pragma("unroll")
  for (int j = 0; j < 4; ++j)
    _Pragma("unroll")
    for (int kc = 0; kc < 2; ++kc)
      koff[j][kc] = ((j*16 + lq)*64 + (((kc*4 + lg) ^ (lq & 7)) << 3)) * 2;

  f32x4 ctx[2][4];
  _Pragma("unroll")
  for (int g = 0; g < 2; ++g)
    _Pragma("unroll")
    for (int d = 0; d < 4; ++d) ctx[g][d] = (f32x4){0.f,0.f,0.f,0.f};
  f32x4 ls0 = (f32x4){0.f,0.f,0.f,0.f};
  f32x4 ls1 = (f32x4){0.f,0.f,0.f,0.f};
  float m0v = -1e30f, m1v = -1e30f;

  const int ntiles = CAUSAL ? (2*qtile + 2) : (KLn >> 6);
  const int P = (ntiles > half) ? ((ntiles - half + 1) >> 1) : 0;

  auto stageA = [&](u16* dK, u16* dV, int tile){
    const u16* kgs = kg + ((size_t)tile << 12);
    const u16* vgs = vg + tile*64;
    gload_lds16(kgs + w*1024 + l*8,       dK + w*1024 + l*8);
    gload_lds16(kgs + w*1024 + 512 + l*8, dK + w*1024 + 512 + l*8);
    gload_lds16(vgs + (size_t)(w*16 +     (l>>3))*KLn + (l&7)*8, dV + w*1024 + l*8);
    gload_lds16(vgs + (size_t)(w*16 + 8 + (l>>3))*KLn + (l&7)*8, dV + w*1024 + 512 + l*8);
  };

#define ABODY(BUF, II)                                                        \
  {                                                                           \
    const int TT = half + 2*(II);                                             \
    f32x4 bv[4];                                                              \
    if (!CAUSAL){                                                             \
      _Pragma("unroll")                                                       \
      for (int sub = 0; sub < 4; ++sub)                                       \
        bv[sub] = *(const f32x4*)(bias + b*KLn + TT*64 + sub*16 + lg*4);      \
    }                                                                         \
    { const int i2 = (II) + 2;                                                \
      const int ts = (i2 < P) ? half + 2*i2 : half;                           \
      stageA(Kl[((BUF)+2)&3], Vl[((BUF)+2)&3], ts); }                         \
    if (CAUSAL) asm volatile("s_waitcnt vmcnt(8)" ::: "memory");              \
    else        asm volatile("s_waitcnt vmcnt(12)" ::: "memory");             \
    __builtin_amdgcn_s_barrier();                                             \
    __builtin_amdgcn_sched_barrier(0);                                        \
    f32x4 s[2][4];                                                            \
    _Pragma("unroll")                                                         \
    for (int g = 0; g < 2; ++g)                                               \
      _Pragma("unroll")                                                       \
      for (int sub = 0; sub < 4; ++sub) s[g][sub] = (f32x4){0.f,0.f,0.f,0.f}; \
    _Pragma("unroll")                                                         \
    for (int sub = 0; sub < 4; ++sub)                                         \
      _Pragma("unroll")                                                       \
      for (int kc = 0; kc < 2; ++kc){                                         \
        short8 bk = *(const short8*)((const char*)Kl + (BUF)*8192 + koff[sub][kc]); \
        s[0][sub] = __builtin_amdgcn_mfma_f32_16x16x32_bf16(bk, aq[0][kc], s[0][sub], 0,0,0); \
        s[1][sub] = __builtin_amdgcn_mfma_f32_16x16x32_bf16(bk, aq[1][kc], s[1][sub], 0,0,0); \
      }                                                                       \
    if (CAUSAL){                                                              \
      if (TT*64 + 63 > rw){                                                   \
        _Pragma("unroll")                                                     \
        for (int g = 0; g < 2; ++g)                                           \
          _Pragma("unroll")                                                   \
          for (int sub = 0; sub < 4; ++sub)                                   \
            _Pragma("unroll")                                                 \
            for (int rr = 0; rr < 4; ++rr)                                    \
              if (TT*64 + sub*16 + lg*4 + rr > rw + g*16 + lq) s[g][sub][rr] = -1e30f; \
      }                                                                       \
    } else {                                                                  \
      _Pragma("unroll")                                                       \
      for (int g = 0; g < 2; ++g)                                             \
        _Pragma("unroll")                                                     \
        for (int sub = 0; sub < 4; ++sub) s[g][sub] += bv[sub];               \
    }                                                                         \
    float px0 = s[0][0][0], px1 = s[1][0][0];                                 \
    _Pragma("unroll")                                                         \
    for (int sub = 0; sub < 4; ++sub)                                         \
      _Pragma("unroll")                                                       \
      for (int rr = 0; rr < 4; ++rr){                                         \
        px0 = fmaxf(px0, s[0][sub][rr]);                                      \
        px1 = fmaxf(px1, s[1][sub][rr]);                                      \
      }                                                                       \
    if (!__all(px0 <= m0v + 8.0f && px1 <= m1v + 8.0f)){                      \
      px0 = fmaxf(px0, __shfl_xor(px0, 16));                                  \
      px0 = fmaxf(px0, __shfl_xor(px0, 32));                                  \
      px1 = fmaxf(px1, __shfl_xor(px1, 16));                                  \
      px1 = fmaxf(px1, __shfl_xor(px1, 32));                                  \
      const float mn0 = fmaxf(m0v, px0), mn1 = fmaxf(m1v, px1);               \
      const float c0 = exp2f(m0v - mn0), c1 = exp2f(m1v - mn1);               \
      ls0 *= c0; ls1 *= c1;                                                   \
      _Pragma("unroll")                                                       \
      for (int rr = 0; rr < 4; ++rr){                                         \
        const float b0 = __shfl(c0, lg*4 + rr), b1 = __shfl(c1, lg*4 + rr);   \
        _Pragma("unroll")                                                     \
        for (int d = 0; d < 4; ++d){ ctx[0][d][rr] *= b0; ctx[1][d][rr] *= b1; } \
      }                                                                       \
      m0v = mn0; m1v = mn1;                                                   \
    }                                                                         \
    u32 pk0[4][2], pk1[4][2];                                                 \
    _Pragma("unroll")                                                         \
    for (int sub = 0; sub < 4; ++sub){                                        \
      float a0 = exp2f(s[0][sub][0] - m0v), a1 = exp2f(s[0][sub][1] - m0v);   \
      float a2 = exp2f(s[0][sub][2] - m0v), a3 = exp2f(s[0][sub][3] - m0v);   \
      ls0 += (f32x4){a0, a1, a2, a3};                                         \
      pk0[sub][0] = cvtpk(a0, a1); pk0[sub][1] = cvtpk(a2, a3);               \
      float e0 = exp2f(s[1][sub][0] - m1v), e1 = exp2f(s[1][sub][1] - m1v);   \
      float e2 = exp2f(s[1][sub][2] - m1v), e3 = exp2f(s[1][sub][3] - m1v);   \
      ls1 += (f32x4){e0, e1, e2, e3};                                         \
      pk1[sub][0] = cvtpk(e0, e1); pk1[sub][1] = cvtpk(e2, e3);               \
    }                                                                         \
    union { u32 u[4]; short8 s8; } pA0, pA1, pB0, pB1;                        \
    pA0.u[0] = pk0[0][0]; pA0.u[1] = pk0[0][1]; pA0.u[2] = pk0[1][0]; pA0.u[3] = pk0[1][1]; \
    pA1.u[0] = pk0[2][0]; pA1.u[1] = pk0[2][1]; pA1.u[2] = pk0[3][0]; pA1.u[3] = pk0[3][1]; \
    pB0.u[0] = pk1[0][0]; pB0.u[1] = pk1[0][1]; pB0.u[2] = pk1[1][0]; pB0.u[3] = pk1[1][1]; \
    pB1.u[0] = pk1[2][0]; pB1.u[1] = pk1[2][1]; pB1.u[2] = pk1[3][0]; pB1.u[3] = pk1[3][1]; \
    _Pragma("unroll")                                                         \
    for (int d0 = 0; d0 < 4; ++d0){                                           \
      short8 v0 = *(const short8*)((const char*)Vl + (BUF)*8192 + koff[d0][0]); \
      short8 v1 = *(const short8*)((const char*)Vl + (BUF)*8192 + koff[d0][1]); \
      ctx[0][d0] = __builtin_amdgcn_mfma_f32_16x16x32_bf16(pA0.s8, v0, ctx[0][d0], 0,0,0); \
      ctx[0][d0] = __builtin_amdgcn_mfma_f32_16x16x32_bf16(pA1.s8, v1, ctx[0][d0], 0,0,0); \
      ctx[1][d0] = __builtin_amdgcn_mfma_f32_16x16x32_bf16(pB0.s8, v0, ctx[1][d0], 0,0,0); \
      ctx[1][d0] = __builtin_amdgcn_mfma_f32_16x16x32_bf16(pB1.s8, v1, ctx[1][d0], 0,0,0); \
    }                                                                         \
  }

  if (P > 0){
    stageA(Kl[0], Vl[0], half);
    { const int ts1 = (1 < P) ? half + 2 : half;
      stageA(Kl[1], Vl[1], ts1); }
    for (int i = 0; i < P; i += 4){
      ABODY(0, i)
      if (i + 1 < P) ABODY(1, i + 1)
      if (i + 2 < P) ABODY(2, i + 2)
      if (i + 3 < P) ABODY(3, i + 3)
    }
  }
#undef ABODY

  // ---- write bf16 partials (merge fused into the O-proj GEMM)
  float h0 = (ls0[0] + ls0[1]) + (ls0[2] + ls0[3]);
  float h1 = (ls1[0] + ls1[1]) + (ls1[2] + ls1[3]);
  h0 += __shfl_xor(h0, 16); h0 += __shfl_xor(h0, 32);
  h1 += __shfl_xor(h1, 16); h1 += __shfl_xor(h1, 32);
  if (lg == 0){
    mlb[((size_t)((half*NB + b)*NH + h) << 11) + rw + lq]      = make_float2(m0v, h0);
    mlb[((size_t)((half*NB + b)*NH + h) << 11) + rw + 16 + lq] = make_float2(m1v, h1);
  }
  u16* cp = ctxp + (size_t)half*MROWS*DIM;
  _Pragma("unroll")
  for (int g = 0; g < 2; ++g)
    _Pragma("unroll")
    for (int d0 = 0; d0 < 4; ++d0)
      _Pragma("unroll")
      for (int rr = 0; rr < 4; ++rr)
        cp[(size_t)(b*QL + rw + g*16 + lg*4 + rr)*DIM + h*DH + d0*16 + lq] =
            f2b(ctx[g][d0][rr]);
}

// ---------------------------------------------------------------- layernorm v2
__global__ __launch_bounds__(128)
void ln_kernel2(const float* __restrict__ in0,
                const float* __restrict__ g, const float* __restrict__ bvec,
                u16* __restrict__ outb)
{
  const int row = blockIdx.x;
  const int t = threadIdx.x;
  const int c0 = t * 4;
  const f32x4 v = *(const f32x4*)&in0[(size_t)row*DIM + c0];
  float s = (v[0] + v[1]) + (v[2] + v[3]);
  #pragma unroll
  for (int off = 1; off < 64; off <<= 1) s += __shfl_xor(s, off);
  __shared__ float red[4];
  if ((t & 63) == 0) red[t >> 6] = s;
  __syncthreads();
  const float mean = (red[0] + red[1]) * (1.f/512.f);
  float q = 0.f;
  #pragma unroll
  for (int i = 0; i < 4; ++i){ const float d = v[i]-mean; q += d*d; }
  #pragma unroll
  for (int off = 1; off < 64; off <<= 1) q += __shfl_xor(q, off);
  if ((t & 63) == 0) red[2 + (t >> 6)] = q;
  __syncthreads();
  const float var = (red[2] + red[3]) * (1.f/512.f);
  const float rs = rsqrtf(var + 1e-5f);
  const f32x4 gg = *(const f32x4*)&g[c0];
  const f32x4 bb = *(const f32x4*)&bvec[c0];
  float y[4];
  #pragma unroll
  for (int i = 0; i < 4; ++i) y[i] = (v[i] - mean) * rs * gg[i] + bb[i];
  uint2 o; o.x = cvtpk(y[0], y[1]); o.y = cvtpk(y[2], y[3]);
  *(uint2*)&outb[(size_t)row*DIM + c0] = o;
}

// ---------------------------------------------------------------- fused prep+LN0
__global__ __launch_bounds__(256)
void prep_ln(const float* w0, const float* w1, const float* w2, const float* w3,
             const float* w4, const float* w5, const float* w6, const float* w7,
             const float* __restrict__ mem, const int* __restrict__ mkpm,
             const float* saqb, const float* sakb, const float* savb,
             const float* cakb, const float* cavb,
             u16* __restrict__ wtA, u16* __restrict__ memb,
             float* __restrict__ bias, float* __restrict__ bc0,
             float* __restrict__ bc1,
             const float* __restrict__ tgt, const float* __restrict__ pos,
             const float* __restrict__ tkpm,
             const float* __restrict__ n1g, const float* __restrict__ n1b,
             float* __restrict__ xres, u16* __restrict__ t2n)
{
  __shared__ float tile[32][33];
  __shared__ float red8[8];
  const int id = blockIdx.x;
  const int tid = threadIdx.x;
  if (id < 2048){
    const int z = id >> 8, rem = id & 255;
    const int r0 = (rem >> 4) * 32, c0 = (rem & 15) * 32;
    const float* wp[8] = {w0,w1,w2,w3,w4,w5,w6,w7};
    const float* w = wp[z];
    u16* o = wtA + (size_t)z * 512 * 512;
    const int tx = tid & 31, ty = tid >> 5;
    #pragma unroll
    for (int i = 0; i < 4; ++i)
      tile[ty + i*8][tx] = w[(size_t)(r0 + ty + i*8)*512 + c0 + tx];
    __syncthreads();
    #pragma unroll
    for (int i = 0; i < 4; ++i)
      o[(size_t)(c0 + ty + i*8)*512 + r0 + tx] = f2b(tile[tx][ty + i*8]);
  } else if (id < 4096){
    const int i = (id - 2048)*1024 + tid*4;
    f32x4 v = *(const f32x4*)&mem[i];
    uint2 p; p.x = cvtpk(v[0], v[1]); p.y = cvtpk(v[2], v[3]);
    *(uint2*)&memb[i] = p;
  } else if (id < 4112){
    const int j = (id - 4096)*256 + tid;   // 0..4095
    bias[j] = mkpm[j] ? 0.f : -1e30f;
    if (j < 1536) bc0[j] = (j < 512) ? saqb[j] : (j < 1024) ? sakb[j-512] : savb[j-1024];
    if (j < 1024) bc1[j] = (j < 512) ? cakb[j] : cavb[j-512];
  } else {
    // LayerNorm 0: x = tgt+pos -> xres; t2n = (LN(x)*g+b)*tkpm[row]
    const int row = id - 4112;
    const int c0 = tid * 2;
    const float2 tg = *(const float2*)&tgt[(size_t)row*DIM + c0];
    const float2 pp = *(const float2*)&pos[(size_t)row*DIM + c0];
    float v[2] = {tg.x + pp.x, tg.y + pp.y};
    *(float2*)&xres[(size_t)row*DIM + c0] = make_float2(v[0], v[1]);
    float s = v[0] + v[1];
    #pragma unroll
    for (int off = 1; off < 64; off <<= 1) s += __shfl_xor(s, off);
    if ((tid & 63) == 0) red8[tid >> 6] = s;
    __syncthreads();
    const float mean = (red8[0] + red8[1] + red8[2] + red8[3]) * (1.f/512.f);
    float q = 0.f;
    #pragma unroll
    for (int i = 0; i < 2; ++i){ const float d = v[i]-mean; q += d*d; }
    #pragma unroll
    for (int off = 1; off < 64; off <<= 1) q += __shfl_xor(q, off);
    if ((tid & 63) == 0) red8[4 + (tid >> 6)] = q;
    __syncthreads();
    const float var = (red8[4] + red8[5] + red8[6] + red8[7]) * (1.f/512.f);
    const float rs = rsqrtf(var + 1e-5f);
    const float tk = tkpm[row];
    const float2 gg = *(const float2*)&n1g[c0];
    const float2 bb = *(const float2*)&n1b[c0];
    const float y0 = ((v[0] - mean) * rs * gg.x + bb.x) * tk;
    const float y1 = ((v[1] - mean) * rs * gg.y + bb.y) * tk;
    *(u32*)&t2n[(size_t)row*DIM + c0] = cvtpk(y0, y1);
  }
}

// V [b][kv][512] -> Vth [b][h][dh][kv'] with PV K-slot permutation AND
// bank XOR-swizzle folded into the kv index. (standalone, self-attn side)
__global__ __launch_bounds__(256)
void transpose_vperm(const u16* __restrict__ in, u16* __restrict__ out)
{
  __shared__ u16 tile[32][33];
  in  += (size_t)blockIdx.z * KLn * DIM;
  out += (size_t)blockIdx.z * NH * DH * KLn;
  const int tx = threadIdx.x, ty = threadIdx.y;
  const int r0 = blockIdx.y*32, c0 = blockIdx.x*32;   // r=kv, c=dcol
  #pragma unroll
  for (int i = 0; i < 4; ++i)
    tile[ty + i*8][tx] = in[(size_t)(r0 + ty + i*8)*DIM + c0 + tx];
  __syncthreads();
  const int kv = r0 + tx;
  const int s  = (kv & ~31) | (((kv>>2)&3)<<3) | (((kv>>4)&1)<<2) | (kv&3);
  #pragma unroll
  for (int i = 0; i < 4; ++i){
    const int dcol = c0 + ty + i*8;
    const int hh = dcol >> 6, dh = dcol & 63;
    const int kvpos = (s & ~63) | (((((s>>3)&7) ^ (dh&7)) << 3)) | (s & 7);
    out[((size_t)(hh*DH + dh))*KLn + kvpos] = tile[tx][ty + i*8];
  }
}

// Cross-side fused: V perm-transpose (blocks 0..2047) + l1w^T (2048..3071)
// + l2w^T (3072..4095).
__global__ __launch_bounds__(256)
void prep_cross(const u16* __restrict__ vb, u16* __restrict__ vt,
                const float* __restrict__ l1w, u16* __restrict__ l1wt,
                const float* __restrict__ l2w, u16* __restrict__ l2wt)
{
  const int id = blockIdx.x;
  const int tid = threadIdx.x;
  const int tx = tid & 31, ty = tid >> 5;
  if (id < 2048){
    __shared__ u16 tileu[32][33];
    const int z = id >> 10, rem = id & 1023;
    const int c0 = (rem & 15) * 32, r0 = (rem >> 4) * 32;
    const u16* in = vb + (size_t)z * KLn * DIM;
    u16* out = vt + (size_t)z * NH * DH * KLn;
    #pragma unroll
    for (int i = 0; i < 4; ++i)
      tileu[ty + i*8][tx] = in[(size_t)(r0 + ty + i*8)*DIM + c0 + tx];
    __syncthreads();
    const int kv = r0 + tx;
    const int s  = (kv & ~31) | (((kv>>2)&3)<<3) | (((kv>>4)&1)<<2) | (kv&3);
    #pragma unroll
    for (int i = 0; i < 4; ++i){
      const int dcol = c0 + ty + i*8;
      const int hh = dcol >> 6, dh = dcol & 63;
      const int kvpos = (s & ~63) | (((((s>>3)&7) ^ (dh&7)) << 3)) | (s & 7);
      out[((size_t)(hh*DH + dh))*KLn + kvpos] = tileu[tx][ty + i*8];
    }
  } else {
    __shared__ float tilef[32][33];
    if (id < 3072){
      const int rem = id - 2048;
      const int c0 = (rem & 63) * 32, r0 = (rem >> 6) * 32;
      #pragma unroll
      for (int i = 0; i < 4; ++i)
        tilef[ty + i*8][tx] = l1w[(size_t)(r0 + ty + i*8)*FFD + c0 + tx];
      __syncthreads();
      #pragma unroll
      for (int i = 0; i < 4; ++i)
        l1wt[(size_t)(c0 + ty + i*8)*512 + r0 + tx] = f2b(tilef[tx][ty + i*8]);
    } else {
      const int rem = id - 3072;
      const int c0 = (rem & 15) * 32, r0 = (rem >> 4) * 32;
      #pragma unroll
      for (int i = 0; i < 4; ++i)
        tilef[ty + i*8][tx] = l2w[(size_t)(r0 + ty + i*8)*512 + c0 + tx];
      __syncthreads();
      #pragma unroll
      for (int i = 0; i < 4; ++i)
        l2wt[(size_t)(c0 + ty + i*8)*FFD + r0 + tx] = f2b(tilef[tx][ty + i*8]);
    }
  }
}

// ---------------------------------------------------------------- launch
extern "C" void kernel_launch(void* const* d_in, const int* in_sizes, int n_in,
                              void* d_out, int out_size, void* d_ws, size_t ws_size,
                              hipStream_t stream)
{
  const float* tgt  = (const float*)d_in[1];
  const float* mem  = (const float*)d_in[2];
  const float* pos  = (const float*)d_in[3];
  const float* tkpm = (const float*)d_in[5];
  const int*   mkpm = (const int*)d_in[6];
  const float* saqw = (const float*)d_in[7];  const float* saqb = (const float*)d_in[8];
  const float* sakw = (const float*)d_in[9];  const float* sakb = (const float*)d_in[10];
  const float* savw = (const float*)d_in[11]; const float* savb = (const float*)d_in[12];
  const float* saow = (const float*)d_in[13]; const float* saob = (const float*)d_in[14];
  const float* caqw = (const float*)d_in[15]; const float* caqb = (const float*)d_in[16];
  const float* cakw = (const float*)d_in[17]; const float* cakb = (const float*)d_in[18];
  const float* cavw = (const float*)d_in[19]; const float* cavb = (const float*)d_in[20];
  const float* caow = (const float*)d_in[21]; const float* caob = (const float*)d_in[22];
  const float* l1w  = (const float*)d_in[23]; const float* l1b  = (const float*)d_in[24];
  const float* l2w  = (const float*)d_in[25]; const float* l2b  = (const float*)d_in[26];
  const float* n1g  = (const float*)d_in[27]; const float* n1b  = (const float*)d_in[28];
  const float* n2g  = (const float*)d_in[29]; const float* n2b  = (const float*)d_in[30];
  const float* n3g  = (const float*)d_in[31]; const float* n3b  = (const float*)d_in[32];

  if (ws_size < 58720256) return;  // 56 MB scratch

  char* ws = (char*)d_ws;
  float* xres = (float*)(ws);
  u16* t2n    = (u16*)(ws + (8u<<20));
  u16* qb     = (u16*)(ws + (12u<<20));
  u16* kb     = (u16*)(ws + (16u<<20));
  u16* vb     = (u16*)(ws + (20u<<20));
  u16* vt     = (u16*)(ws + (24u<<20));
  float* bias = (float*)(ws + (28u<<20));              // 16 KB
  float* bc0  = (float*)(ws + (28u<<20) + 16384);      // 6 KB
  float* bc1  = (float*)(ws + (28u<<20) + 24576);      // 4 KB
  float2* mlb = (float2*)(ws + (28u<<20) + 32768);     // 512 KB
  u16* l1wt   = (u16*)(ws + (29u<<20));
  u16* l2wt   = (u16*)(ws + (31u<<20));
  u16* memb   = (u16*)(ws + (33u<<20));
  u16* wtA    = (u16*)(ws + (37u<<20));
  u16* ctxp   = (u16*)(ws + (41u<<20));
  u16* ffh    = (u16*)(ws + (12u<<20));   // aliases qb..vt (dead by FF phase)

  float* out = (float*)d_out;
  const int W55 = 512*512;

  prep_ln<<<dim3(8208), 256, 0, stream>>>(saqw, sakw, savw, saow,
                                          caqw, cakw, cavw, caow,
                                          mem, mkpm, saqb, sakb, savb, cakb, cavb,
                                          wtA, memb, bias, bc0, bc1,
                                          tgt, pos, tkpm, n1g, n1b, xres, t2n);

  #define G(EP, GX) gemm64<EP><<<dim3(GX,64), 256, 0, stream>>>

  // ---- self attention (fused QKV: N=1536; merge fused into O-proj)
  G(EPI_QKV, 24)(t2n, wtA, bc0, qb, nullptr, nullptr, nullptr, 512, 1536);
  transpose_vperm<<<dim3(DIM/32, KLn/32, NB), dim3(32,8), 0, stream>>>(vb, vt);
  attn8<true><<<dim3(QL/128, NH, NB*2), 256, 0, stream>>>(qb, kb, vt, nullptr, ctxp, mlb);
  gemm_om<<<dim3(8,64), 256, 0, stream>>>(ctxp, mlb, wtA + 3*W55, saob, xres);

  ln_kernel2<<<MROWS, 128, 0, stream>>>(xres, n2g, n2b, t2n);

  // ---- cross attention (Q + KV projections in ONE launch; merge fused into O-proj)
  gemm_cross<<<dim3(24,64), 256, 0, stream>>>(t2n, memb, wtA + 4*W55, wtA + 5*W55,
                                              caqb, bc1, qb, kb);
  prep_cross<<<dim3(4096), 256, 0, stream>>>(vb, vt, l1w, l1wt, l2w, l2wt);
  attn8<false><<<dim3(QL/128, NH, NB*2), 256, 0, stream>>>(qb, kb, vt, bias, ctxp, mlb);
  gemm_om<<<dim3(8,64), 256, 0, stream>>>(ctxp, mlb, wtA + 7*W55, caob, xres);

  ln_kernel2<<<MROWS, 128, 0, stream>>>(xres, n3g, n3b, t2n);

  // ---- feed-forward (FF2 epilogue fuses residual add + tkpm scale + f32 out)
  G(EPI_RELU, 32)(t2n, l1wt, l1b, ffh, nullptr, nullptr, nullptr, 512, FFD);
  G(EPI_FIN, 8)(ffh, l2wt, l2b, nullptr, xres, tkpm, out, 2048, 512);

  #undef G
}

// Round 23
// 186.097 us; speedup vs baseline: 1.0365x; 1.0365x over previous
//
#include <hip/hip_runtime.h>
#include <hip/hip_bf16.h>
#include <stdint.h>

#define QL   2048
#define KLn  2048
#define DIM  512
#define NH   8
#define DH   64
#define NB   2
#define MROWS (NB*QL)   // 4096
#define FFD  2048

typedef unsigned short u16;
typedef unsigned int u32;
typedef __attribute__((ext_vector_type(8))) short short8;
typedef __attribute__((ext_vector_type(4))) float f32x4;

__device__ __forceinline__ u16 f2b(float f){
  union { float f; u32 i; } v; v.f = f;
  u32 r = v.i + 0x7FFFu + ((v.i >> 16) & 1u);
  return (u16)(r >> 16);
}
__device__ __forceinline__ float b2f(u16 u){
  union { u32 i; float f; } v; v.i = ((u32)u) << 16; return v.f;
}
// two f32 -> packed bf16x2 in one instruction (lo=a, hi=b, RNE)
__device__ __forceinline__ u32 cvtpk(float a, float b){
  u32 r;
  asm("v_cvt_pk_bf16_f32 %0, %1, %2" : "=v"(r) : "v"(a), "v"(b));
  return r;
}

typedef __attribute__((address_space(3))) void as3void;
typedef __attribute__((address_space(1))) void as1void;
__device__ __forceinline__ void gload_lds16(const void* g, void* l){
  __builtin_amdgcn_global_load_lds((as1void*)g, (as3void*)l, 16, 0, 0);
}

// ---------------------------------------------------------------- GEMM (64x64)
#define BK 64
enum { EPI_BIAS=0, EPI_SCALEQ=1, EPI_RELU=2, EPI_RES=3, EPI_FIN=5, EPI_QKV=6, EPI_KV=7 };
// 1/sqrt(64) * log2(e): folds softmax exp->exp2 conversion into Q scale
#define QSCALE 0.1803368801111244f

template<int EPI>
__global__ __launch_bounds__(256, 4)
void gemm64(const u16* __restrict__ A, const u16* __restrict__ Bt,
            const float* __restrict__ bias,
            u16* __restrict__ Obf, float* __restrict__ Ores,
            const float* __restrict__ tk, float* __restrict__ fout,
            int K, int N)
{
  __shared__ __align__(16) u16 As[2][64*BK];
  __shared__ __align__(16) u16 Bs[2][64*BK];
  const int t  = threadIdx.x;
  const int l  = t & 63;
  const int lq = l & 15, lg = l >> 4;
  const int w  = t >> 6;
  const int wm = (w >> 1) * 32;
  const int wn = (w & 1) * 32;

  const int gx   = gridDim.x;
  const int nwg  = gx * gridDim.y;
  const int orig = blockIdx.x + gx * blockIdx.y;
  const int wgid = (orig & 7) * (nwg >> 3) + (orig >> 3);
  const int m0 = (wgid / gx) * 64;
  const int n0 = (wgid % gx) * 64;

  const int srow = t >> 3;   // 0..31
  const int scs  = t & 7;

  auto stageG = [&](u16* dA, u16* dB, int k0){
    _Pragma("unroll")
    for (int i = 0; i < 2; ++i){
      const int row = i*32 + srow;
      gload_lds16(A  + (size_t)(m0 + row)*K + k0 + ((scs ^ (row & 7)) << 3),
                  dA + row*BK + scs*8);
      gload_lds16(Bt + (size_t)(n0 + row)*K + k0 + ((scs ^ (row & 7)) << 3),
                  dB + row*BK + scs*8);
    }
  };

  int aoff[2][2], boff[2][2];
  _Pragma("unroll")
  for (int i = 0; i < 2; ++i)
    _Pragma("unroll")
    for (int kc = 0; kc < 2; ++kc){
      const int sw = (((kc*4 + lg) ^ (lq & 7)) << 3);
      aoff[i][kc] = ((wm + i*16 + lq)*BK + sw) * 2;
      boff[i][kc] = ((wn + i*16 + lq)*BK + sw) * 2;
    }

  f32x4 acc[2][2];
  _Pragma("unroll")
  for (int i=0;i<2;i++)
    _Pragma("unroll")
    for (int j=0;j<2;j++) acc[i][j] = (f32x4){0.f,0.f,0.f,0.f};

#define GBODY(BUF, KK)                                                        \
  {                                                                           \
    { const int ks = ((KK) + BK < K) ? (KK) + BK : 0;                         \
      stageG(As[(BUF)^1], Bs[(BUF)^1], ks); }                                 \
    asm volatile("s_waitcnt vmcnt(4)" ::: "memory");                          \
    __builtin_amdgcn_s_barrier();                                             \
    __builtin_amdgcn_sched_barrier(0);                                        \
    short8 af[2][2], bf[2][2];                                                \
    _Pragma("unroll")                                                         \
    for (int kc = 0; kc < 2; ++kc)                                            \
      _Pragma("unroll")                                                       \
      for (int i = 0; i < 2; ++i){                                            \
        af[i][kc] = *(const short8*)((const char*)As + (BUF)*8192 + aoff[i][kc]); \
        bf[i][kc] = *(const short8*)((const char*)Bs + (BUF)*8192 + boff[i][kc]); \
      }                                                                       \
    __builtin_amdgcn_s_barrier();                                             \
    __builtin_amdgcn_s_setprio(1);                                            \
    _Pragma("unroll")                                                         \
    for (int kc = 0; kc < 2; ++kc)                                            \
      _Pragma("unroll")                                                       \
      for (int i = 0; i < 2; ++i)                                             \
        _Pragma("unroll")                                                     \
        for (int j = 0; j < 2; ++j)                                           \
          acc[i][j] = __builtin_amdgcn_mfma_f32_16x16x32_bf16(af[i][kc], bf[j][kc], acc[i][j], 0,0,0); \
    __builtin_amdgcn_s_setprio(0);                                            \
  }

  stageG(As[0], Bs[0], 0);
  for (int k0 = 0; k0 < K; k0 += 2*BK){
    GBODY(0, k0)
    GBODY(1, k0 + BK)
  }
#undef GBODY

  _Pragma("unroll")
  for (int i=0;i<2;i++){
    _Pragma("unroll")
    for (int j=0;j<2;j++){
      _Pragma("unroll")
      for (int rr=0;rr<4;rr++){
        const int row = m0 + wm + i*16 + lg*4 + rr;
        const int col = n0 + wn + j*16 + lq;
        float v = acc[i][j][rr] + bias[col];
        if (EPI == EPI_SCALEQ) v *= QSCALE;
        if (EPI == EPI_RELU)   v = fmaxf(v, 0.f);
        if (EPI == EPI_RES)    Ores[(size_t)row*N + col] += v;
        else if (EPI == EPI_FIN){
          const size_t idx = (size_t)row*N + col;
          fout[idx] = (Ores[idx] + v) * tk[row];
        }
        else if (EPI == EPI_QKV){
          const int seg = col >> 9, c = col & 511;
          if (seg == 0)      Obf[(size_t)row*512 + c] = f2b(v * QSCALE);
          else if (seg == 1){
            const int bb = row >> 11, kv = row & 2047;
            const int hh = c >> 6,  dh = c & 63;
            Obf[(2u<<20) + ((((size_t)(bb*NH + hh) << 11) + kv) << 6) + (dh ^ ((kv & 7) << 3))] = f2b(v);
          }
          else               Obf[(4u<<20) + (size_t)row*512 + c] = f2b(v);
        }
        else if (EPI == EPI_KV){
          const int seg = col >> 9, c = col & 511;
          if (seg == 0){
            const int bb = row >> 11, kv = row & 2047;
            const int hh = c >> 6,  dh = c & 63;
            Obf[((((size_t)(bb*NH + hh) << 11) + kv) << 6) + (dh ^ ((kv & 7) << 3))] = f2b(v);
          }
          else               Obf[(2u<<20) + (size_t)row*512 + c] = f2b(v);
        }
        else                   Obf[(size_t)row*N + col] = f2b(v);
      }
    }
  }
}

// ---------------------------------------------------------------- cross-QKV
// Fused launch of the two INDEPENDENT cross-attn projections.
__global__ __launch_bounds__(256, 4)
void gemm_cross(const u16* __restrict__ t2n_, const u16* __restrict__ memb_,
                const u16* __restrict__ BtQ, const u16* __restrict__ BtKV,
                const float* __restrict__ biasQ, const float* __restrict__ biasKV,
                u16* __restrict__ qb_, u16* __restrict__ kb_)
{
  const int K = 512;
  __shared__ __align__(16) u16 As[2][64*BK];
  __shared__ __align__(16) u16 Bs[2][64*BK];
  const int t  = threadIdx.x;
  const int l  = t & 63;
  const int lq = l & 15, lg = l >> 4;
  const int w  = t >> 6;
  const int wm = (w >> 1) * 32;
  const int wn = (w & 1) * 32;

  const int gx   = gridDim.x;                 // 24
  const int nwg  = gx * gridDim.y;            // 1536
  const int orig = blockIdx.x + gx * blockIdx.y;
  const int wgid = (orig & 7) * (nwg >> 3) + (orig >> 3);
  const int part = (wgid < 512) ? 0 : 1;
  const int id   = part ? wgid - 512 : wgid;
  const int gxp  = part ? 16 : 8;
  const int m0 = (id / gxp) * 64;
  const int n0 = (id % gxp) * 64;

  const u16* A   = part ? memb_ : t2n_;
  const u16* Bt  = part ? BtKV  : BtQ;
  const float* bias = part ? biasKV : biasQ;

  const int srow = t >> 3;
  const int scs  = t & 7;

  auto stageG = [&](u16* dA, u16* dB, int k0){
    _Pragma("unroll")
    for (int i = 0; i < 2; ++i){
      const int row = i*32 + srow;
      gload_lds16(A  + (size_t)(m0 + row)*K + k0 + ((scs ^ (row & 7)) << 3),
                  dA + row*BK + scs*8);
      gload_lds16(Bt + (size_t)(n0 + row)*K + k0 + ((scs ^ (row & 7)) << 3),
                  dB + row*BK + scs*8);
    }
  };

  int aoff[2][2], boff[2][2];
  _Pragma("unroll")
  for (int i = 0; i < 2; ++i)
    _Pragma("unroll")
    for (int kc = 0; kc < 2; ++kc){
      const int sw = (((kc*4 + lg) ^ (lq & 7)) << 3);
      aoff[i][kc] = ((wm + i*16 + lq)*BK + sw) * 2;
      boff[i][kc] = ((wn + i*16 + lq)*BK + sw) * 2;
    }

  f32x4 acc[2][2];
  _Pragma("unroll")
  for (int i=0;i<2;i++)
    _Pragma("unroll")
    for (int j=0;j<2;j++) acc[i][j] = (f32x4){0.f,0.f,0.f,0.f};

#define GBODY(BUF, KK)                                                        \
  {                                                                           \
    { const int ks = ((KK) + BK < K) ? (KK) + BK : 0;                         \
      stageG(As[(BUF)^1], Bs[(BUF)^1], ks); }                                 \
    asm volatile("s_waitcnt vmcnt(4)" ::: "memory");                          \
    __builtin_amdgcn_s_barrier();                                             \
    __builtin_amdgcn_sched_barrier(0);                                        \
    short8 af[2][2], bf[2][2];                                                \
    _Pragma("unroll")                                                         \
    for (int kc = 0; kc < 2; ++kc)                                            \
      _Pragma("unroll")                                                       \
      for (int i = 0; i < 2; ++i){                                            \
        af[i][kc] = *(const short8*)((const char*)As + (BUF)*8192 + aoff[i][kc]); \
        bf[i][kc] = *(const short8*)((const char*)Bs + (BUF)*8192 + boff[i][kc]); \
      }                                                                       \
    __builtin_amdgcn_s_barrier();                                             \
    __builtin_amdgcn_s_setprio(1);                                            \
    _Pragma("unroll")                                                         \
    for (int kc = 0; kc < 2; ++kc)                                            \
      _Pragma("unroll")                                                       \
      for (int i = 0; i < 2; ++i)                                             \
        _Pragma("unroll")                                                     \
        for (int j = 0; j < 2; ++j)                                           \
          acc[i][j] = __builtin_amdgcn_mfma_f32_16x16x32_bf16(af[i][kc], bf[j][kc], acc[i][j], 0,0,0); \
    __builtin_amdgcn_s_setprio(0);                                            \
  }

  stageG(As[0], Bs[0], 0);
  for (int k0 = 0; k0 < K; k0 += 2*BK){
    GBODY(0, k0)
    GBODY(1, k0 + BK)
  }
#undef GBODY

  _Pragma("unroll")
  for (int i=0;i<2;i++){
    _Pragma("unroll")
    for (int j=0;j<2;j++){
      _Pragma("unroll")
      for (int rr=0;rr<4;rr++){
        const int row = m0 + wm + i*16 + lg*4 + rr;
        const int col = n0 + wn + j*16 + lq;
        float v = acc[i][j][rr] + bias[col];
        if (part == 0){
          qb_[(size_t)row*512 + col] = f2b(v * QSCALE);
        } else {
          const int seg = col >> 9, c = col & 511;
          if (seg == 0){
            const int bb = row >> 11, kv = row & 2047;
            const int hh = c >> 6,  dh = c & 63;
            kb_[((((size_t)(bb*NH + hh) << 11) + kv) << 6) + (dh ^ ((kv & 7) << 3))] = f2b(v);
          }
          else kb_[(2u<<20) + (size_t)row*512 + c] = f2b(v);
        }
      }
    }
  }
}

// ---------------------------------------------------------------- O-proj GEMM
// with the flash-decode merge FUSED into the A-operand staging.
__global__ __launch_bounds__(256, 4)
void gemm_om(const u16* __restrict__ ctxp, const float2* __restrict__ mlb,
             const u16* __restrict__ Bt, const float* __restrict__ bias,
             float* __restrict__ Ores)
{
  const int K = 512, N = 512;
  __shared__ __align__(16) u16 As[2][64*BK];
  __shared__ __align__(16) u16 Bs[2][64*BK];
  const int t  = threadIdx.x;
  const int l  = t & 63;
  const int lq = l & 15, lg = l >> 4;
  const int w  = t >> 6;
  const int wm = (w >> 1) * 32;
  const int wn = (w & 1) * 32;

  const int gx   = gridDim.x;
  const int nwg  = gx * gridDim.y;
  const int orig = blockIdx.x + gx * blockIdx.y;
  const int wgid = (orig & 7) * (nwg >> 3) + (orig >> 3);
  const int m0 = (wgid / gx) * 64;
  const int n0 = (wgid % gx) * 64;

  const int srow = t >> 3;   // 0..31
  const int scs  = t & 7;

  typedef __attribute__((ext_vector_type(4))) u32 u32x4;
  union Apack { u32x4 v; u16 e[8]; };

  auto loadA = [&](Apack* c0, Apack* c1, float2* a0, float2* a1, int k0){
    _Pragma("unroll")
    for (int i = 0; i < 2; ++i){
      const int row  = i*32 + srow;
      const int grow = m0 + row;
      const int b_   = grow >> 11, qr = grow & 2047;
      const int kk   = k0 + ((scs ^ (row & 7)) << 3);
      const int h_   = kk >> 6;
      c0[i].v = *(const u32x4*)&ctxp[(size_t)grow*512 + kk];
      c1[i].v = *(const u32x4*)&ctxp[(size_t)MROWS*512 + (size_t)grow*512 + kk];
      a0[i] = mlb[((size_t)(b_*NH + h_) << 11) + qr];
      a1[i] = mlb[((size_t)((NB + b_)*NH + h_) << 11) + qr];
    }
  };
  auto writeA = [&](u16* dA, Apack* c0, Apack* c1, float2* a0, float2* a1){
    _Pragma("unroll")
    for (int i = 0; i < 2; ++i){
      const int row = i*32 + srow;
      const float mg = fmaxf(a0[i].x, a1[i].x);
      const float w0 = exp2f(a0[i].x - mg), w1 = exp2f(a1[i].x - mg);
      const float rd = 1.f / (a0[i].y*w0 + a1[i].y*w1);
      u32x4 o;
      _Pragma("unroll")
      for (int j = 0; j < 4; ++j)
        o[j] = cvtpk((b2f(c0[i].e[2*j  ])*w0 + b2f(c1[i].e[2*j  ])*w1) * rd,
                     (b2f(c0[i].e[2*j+1])*w0 + b2f(c1[i].e[2*j+1])*w1) * rd);
      *(u32x4*)&dA[row*BK + scs*8] = o;
    }
  };
  auto stageB = [&](u16* dB, int k0){
    _Pragma("unroll")
    for (int i = 0; i < 2; ++i){
      const int row = i*32 + srow;
      gload_lds16(Bt + (size_t)(n0 + row)*K + k0 + ((scs ^ (row & 7)) << 3),
                  dB + row*BK + scs*8);
    }
  };

  int aoff[2][2], boff[2][2];
  _Pragma("unroll")
  for (int i = 0; i < 2; ++i)
    _Pragma("unroll")
    for (int kc = 0; kc < 2; ++kc){
      const int sw = (((kc*4 + lg) ^ (lq & 7)) << 3);
      aoff[i][kc] = ((wm + i*16 + lq)*BK + sw) * 2;
      boff[i][kc] = ((wn + i*16 + lq)*BK + sw) * 2;
    }

  f32x4 acc[2][2];
  _Pragma("unroll")
  for (int i=0;i<2;i++)
    _Pragma("unroll")
    for (int j=0;j<2;j++) acc[i][j] = (f32x4){0.f,0.f,0.f,0.f};

  {
    Apack c0[2], c1[2]; float2 a0[2], a1[2];
    loadA(c0, c1, a0, a1, 0);
    stageB(Bs[0], 0);
    writeA(As[0], c0, c1, a0, a1);
  }
  int cur = 0;
  for (int k0 = 0; k0 < K; k0 += BK){
    __syncthreads();                       // A ds_writes + B gloads visible
    short8 af[2][2], bf[2][2];
    _Pragma("unroll")
    for (int kc = 0; kc < 2; ++kc)
      _Pragma("unroll")
      for (int i = 0; i < 2; ++i){
        af[i][kc] = *(const short8*)((const char*)As + cur*8192 + aoff[i][kc]);
        bf[i][kc] = *(const short8*)((const char*)Bs + cur*8192 + boff[i][kc]);
      }
    __syncthreads();                       // reads done; other buf writable
    const bool has = (k0 + BK) < K;
    Apack c0[2], c1[2]; float2 a0[2], a1[2];
    if (has){
      loadA(c0, c1, a0, a1, k0 + BK);      // loads fly under the MFMA block
      stageB(Bs[cur^1], k0 + BK);
    }
    __builtin_amdgcn_s_setprio(1);
    _Pragma("unroll")
    for (int kc = 0; kc < 2; ++kc)
      _Pragma("unroll")
      for (int i = 0; i < 2; ++i)
        _Pragma("unroll")
        for (int j = 0; j < 2; ++j)
          acc[i][j] = __builtin_amdgcn_mfma_f32_16x16x32_bf16(af[i][kc], bf[j][kc], acc[i][j], 0,0,0);
    __builtin_amdgcn_s_setprio(0);
    if (has) writeA(As[cur^1], c0, c1, a0, a1);
    cur ^= 1;
  }

  _Pragma("unroll")
  for (int i=0;i<2;i++){
    _Pragma("unroll")
    for (int j=0;j<2;j++){
      _Pragma("unroll")
      for (int rr=0;rr<4;rr++){
        const int row = m0 + wm + i*16 + lg*4 + rr;
        const int col = n0 + wn + j*16 + lq;
        Ores[(size_t)row*N + col] += acc[i][j][rr] + bias[col];
      }
    }
  }
}

// ---------------------------------------------------------------- attention v8c
// v8b minus the trailing per-body s_barrier (safe with 4-buffer lifecycle).
// Best-known attn config (R20/R21). XCD remap (R22) regressed; reverted.
template<bool CAUSAL>
__global__ __launch_bounds__(256, 2)
void attn8(const u16* __restrict__ Q, const u16* __restrict__ Kbh,
           const u16* __restrict__ Vth, const float* __restrict__ bias,
           u16* __restrict__ ctxp, float2* __restrict__ mlb)
{
  __shared__ __align__(16) u16 Kl[4][64*64];   // 32 KB
  __shared__ __align__(16) u16 Vl[4][64*64];   // 32 KB
  const int tid = threadIdx.x;
  const int l  = tid & 63;
  const int w  = tid >> 6;
  const int lq = l & 15, lg = l >> 4;
  const int h    = blockIdx.y;
  const int b    = blockIdx.z >> 1;
  const int half = blockIdx.z & 1;
  const int qtile = CAUSAL ? ((b & 1) ? (15 - (int)blockIdx.x) : (int)blockIdx.x)
                           : (int)blockIdx.x;
  const int rw = qtile*128 + w*32;             // wave's first q-row

  const u16* kg = Kbh + ((size_t)(b*NH + h) << 17);   // [2048][64]
  const u16* vg = Vth + ((size_t)(b*NH + h) << 17);   // [64][2048]

  short8 aq[2][2];
  _Pragma("unroll")
  for (int g = 0; g < 2; ++g)
    _Pragma("unroll")
    for (int kc = 0; kc < 2; ++kc)
      aq[g][kc] = *(const short8*)(Q + (size_t)(b*QL + rw + g*16 + lq)*DIM + h*DH + kc*32 + lg*8);

  int koff[4][2];
  _Pragma("unroll")
  for (int j = 0; j < 4; ++j)
    _Pragma("unroll")
    for (int kc = 0; kc < 2; ++kc)
      koff[j][kc] = ((j*16 + lq)*64 + (((kc*4 + lg) ^ (lq & 7)) << 3)) * 2;

  f32x4 ctx[2][4];
  _Pragma("unroll")
  for (int g = 0; g < 2; ++g)
    _Pragma("unroll")
    for (int d = 0; d < 4; ++d) ctx[g][d] = (f32x4){0.f,0.f,0.f,0.f};
  f32x4 ls0 = (f32x4){0.f,0.f,0.f,0.f};
  f32x4 ls1 = (f32x4){0.f,0.f,0.f,0.f};
  float m0v = -1e30f, m1v = -1e30f;

  const int ntiles = CAUSAL ? (2*qtile + 2) : (KLn >> 6);
  const int P = (ntiles > half) ? ((ntiles - half + 1) >> 1) : 0;

  auto stageA = [&](u16* dK, u16* dV, int tile){
    const u16* kgs = kg + ((size_t)tile << 12);
    const u16* vgs = vg + tile*64;
    gload_lds16(kgs + w*1024 + l*8,       dK + w*1024 + l*8);
    gload_lds16(kgs + w*1024 + 512 + l*8, dK + w*1024 + 512 + l*8);
    gload_lds16(vgs + (size_t)(w*16 +     (l>>3))*KLn + (l&7)*8, dV + w*1024 + l*8);
    gload_lds16(vgs + (size_t)(w*16 + 8 + (l>>3))*KLn + (l&7)*8, dV + w*1024 + 512 + l*8);
  };

#define ABODY(BUF, II)                                                        \
  {                                                                           \
    const int TT = half + 2*(II);                                             \
    f32x4 bv[4];                                                              \
    if (!CAUSAL){                                                             \
      _Pragma("unroll")                                                       \
      for (int sub = 0; sub < 4; ++sub)                                       \
        bv[sub] = *(const f32x4*)(bias + b*KLn + TT*64 + sub*16 + lg*4);      \
    }                                                                         \
    { const int i2 = (II) + 2;                                                \
      const int ts = (i2 < P) ? half + 2*i2 : half;                           \
      stageA(Kl[((BUF)+2)&3], Vl[((BUF)+2)&3], ts); }                         \
    if (CAUSAL) asm volatile("s_waitcnt vmcnt(8)" ::: "memory");              \
    else        asm volatile("s_waitcnt vmcnt(12)" ::: "memory");             \
    __builtin_amdgcn_s_barrier();                                             \
    __builtin_amdgcn_sched_barrier(0);                                        \
    f32x4 s[2][4];                                                            \
    _Pragma("unroll")                                                         \
    for (int g = 0; g < 2; ++g)                                               \
      _Pragma("unroll")                                                       \
      for (int sub = 0; sub < 4; ++sub) s[g][sub] = (f32x4){0.f,0.f,0.f,0.f}; \
    _Pragma("unroll")                                                         \
    for (int sub = 0; sub < 4; ++sub)                                         \
      _Pragma("unroll")                                                       \
      for (int kc = 0; kc < 2; ++kc){                                         \
        short8 bk = *(const short8*)((const char*)Kl + (BUF)*8192 + koff[sub][kc]); \
        s[0][sub] = __builtin_amdgcn_mfma_f32_16x16x32_bf16(bk, aq[0][kc], s[0][sub], 0,0,0); \
        s[1][sub] = __builtin_amdgcn_mfma_f32_16x16x32_bf16(bk, aq[1][kc], s[1][sub], 0,0,0); \
      }                                                                       \
    if (CAUSAL){                                                              \
      if (TT*64 + 63 > rw){                                                   \
        _Pragma("unroll")                                                     \
        for (int g = 0; g < 2; ++g)                                           \
          _Pragma("unroll")                                                   \
          for (int sub = 0; sub < 4; ++sub)                                   \
            _Pragma("unroll")                                                 \
            for (int rr = 0; rr < 4; ++rr)                                    \
              if (TT*64 + sub*16 + lg*4 + rr > rw + g*16 + lq) s[g][sub][rr] = -1e30f; \
      }                                                                       \
    } else {                                                                  \
      _Pragma("unroll")                                                       \
      for (int g = 0; g < 2; ++g)                                             \
        _Pragma("unroll")                                                     \
        for (int sub = 0; sub < 4; ++sub) s[g][sub] += bv[sub];               \
    }                                                                         \
    float px0 = s[0][0][0], px1 = s[1][0][0];                                 \
    _Pragma("unroll")                                                         \
    for (int sub = 0; sub < 4; ++sub)                                         \
      _Pragma("unroll")                                                       \
      for (int rr = 0; rr < 4; ++rr){                                         \
        px0 = fmaxf(px0, s[0][sub][rr]);                                      \
        px1 = fmaxf(px1, s[1][sub][rr]);                                      \
      }                                                                       \
    if (!__all(px0 <= m0v + 8.0f && px1 <= m1v + 8.0f)){                      \
      px0 = fmaxf(px0, __shfl_xor(px0, 16));                                  \
      px0 = fmaxf(px0, __shfl_xor(px0, 32));                                  \
      px1 = fmaxf(px1, __shfl_xor(px1, 16));                                  \
      px1 = fmaxf(px1, __shfl_xor(px1, 32));                                  \
      const float mn0 = fmaxf(m0v, px0), mn1 = fmaxf(m1v, px1);               \
      const float c0 = exp2f(m0v - mn0), c1 = exp2f(m1v - mn1);               \
      ls0 *= c0; ls1 *= c1;                                                   \
      _Pragma("unroll")                                                       \
      for (int rr = 0; rr < 4; ++rr){                                         \
        const float b0 = __shfl(c0, lg*4 + rr), b1 = __shfl(c1, lg*4 + rr);   \
        _Pragma("unroll")                                                     \
        for (int d = 0; d < 4; ++d){ ctx[0][d][rr] *= b0; ctx[1][d][rr] *= b1; } \
      }                                                                       \
      m0v = mn0; m1v = mn1;                                                   \
    }                                                                         \
    u32 pk0[4][2], pk1[4][2];                                                 \
    _Pragma("unroll")                                                         \
    for (int sub = 0; sub < 4; ++sub){                                        \
      float a0 = exp2f(s[0][sub][0] - m0v), a1 = exp2f(s[0][sub][1] - m0v);   \
      float a2 = exp2f(s[0][sub][2] - m0v), a3 = exp2f(s[0][sub][3] - m0v);   \
      ls0 += (f32x4){a0, a1, a2, a3};                                         \
      pk0[sub][0] = cvtpk(a0, a1); pk0[sub][1] = cvtpk(a2, a3);               \
      float e0 = exp2f(s[1][sub][0] - m1v), e1 = exp2f(s[1][sub][1] - m1v);   \
      float e2 = exp2f(s[1][sub][2] - m1v), e3 = exp2f(s[1][sub][3] - m1v);   \
      ls1 += (f32x4){e0, e1, e2, e3};                                         \
      pk1[sub][0] = cvtpk(e0, e1); pk1[sub][1] = cvtpk(e2, e3);               \
    }                                                                         \
    union { u32 u[4]; short8 s8; } pA0, pA1, pB0, pB1;                        \
    pA0.u[0] = pk0[0][0]; pA0.u[1] = pk0[0][1]; pA0.u[2] = pk0[1][0]; pA0.u[3] = pk0[1][1]; \
    pA1.u[0] = pk0[2][0]; pA1.u[1] = pk0[2][1]; pA1.u[2] = pk0[3][0]; pA1.u[3] = pk0[3][1]; \
    pB0.u[0] = pk1[0][0]; pB0.u[1] = pk1[0][1]; pB0.u[2] = pk1[1][0]; pB0.u[3] = pk1[1][1]; \
    pB1.u[0] = pk1[2][0]; pB1.u[1] = pk1[2][1]; pB1.u[2] = pk1[3][0]; pB1.u[3] = pk1[3][1]; \
    _Pragma("unroll")                                                         \
    for (int d0 = 0; d0 < 4; ++d0){                                           \
      short8 v0 = *(const short8*)((const char*)Vl + (BUF)*8192 + koff[d0][0]); \
      short8 v1 = *(const short8*)((const char*)Vl + (BUF)*8192 + koff[d0][1]); \
      ctx[0][d0] = __builtin_amdgcn_mfma_f32_16x16x32_bf16(pA0.s8, v0, ctx[0][d0], 0,0,0); \
      ctx[0][d0] = __builtin_amdgcn_mfma_f32_16x16x32_bf16(pA1.s8, v1, ctx[0][d0], 0,0,0); \
      ctx[1][d0] = __builtin_amdgcn_mfma_f32_16x16x32_bf16(pB0.s8, v0, ctx[1][d0], 0,0,0); \
      ctx[1][d0] = __builtin_amdgcn_mfma_f32_16x16x32_bf16(pB1.s8, v1, ctx[1][d0], 0,0,0); \
    }                                                                         \
  }

  if (P > 0){
    stageA(Kl[0], Vl[0], half);
    { const int ts1 = (1 < P) ? half + 2 : half;
      stageA(Kl[1], Vl[1], ts1); }
    for (int i = 0; i < P; i += 4){
      ABODY(0, i)
      if (i + 1 < P) ABODY(1, i + 1)
      if (i + 2 < P) ABODY(2, i + 2)
      if (i + 3 < P) ABODY(3, i + 3)
    }
  }
#undef ABODY

  // ---- write bf16 partials (merge fused into the O-proj GEMM)
  float h0 = (ls0[0] + ls0[1]) + (ls0[2] + ls0[3]);
  float h1 = (ls1[0] + ls1[1]) + (ls1[2] + ls1[3]);
  h0 += __shfl_xor(h0, 16); h0 += __shfl_xor(h0, 32);
  h1 += __shfl_xor(h1, 16); h1 += __shfl_xor(h1, 32);
  if (lg == 0){
    mlb[((size_t)((half*NB + b)*NH + h) << 11) + rw + lq]      = make_float2(m0v, h0);
    mlb[((size_t)((half*NB + b)*NH + h) << 11) + rw + 16 + lq] = make_float2(m1v, h1);
  }
  u16* cp = ctxp + (size_t)half*MROWS*DIM;
  _Pragma("unroll")
  for (int g = 0; g < 2; ++g)
    _Pragma("unroll")
    for (int d0 = 0; d0 < 4; ++d0)
      _Pragma("unroll")
      for (int rr = 0; rr < 4; ++rr)
        cp[(size_t)(b*QL + rw + g*16 + lg*4 + rr)*DIM + h*DH + d0*16 + lq] =
            f2b(ctx[g][d0][rr]);
}

// ---------------------------------------------------------------- layernorm v2
__global__ __launch_bounds__(128)
void ln_kernel2(const float* __restrict__ in0,
                const float* __restrict__ g, const float* __restrict__ bvec,
                u16* __restrict__ outb)
{
  const int row = blockIdx.x;
  const int t = threadIdx.x;
  const int c0 = t * 4;
  const f32x4 v = *(const f32x4*)&in0[(size_t)row*DIM + c0];
  float s = (v[0] + v[1]) + (v[2] + v[3]);
  #pragma unroll
  for (int off = 1; off < 64; off <<= 1) s += __shfl_xor(s, off);
  __shared__ float red[4];
  if ((t & 63) == 0) red[t >> 6] = s;
  __syncthreads();
  const float mean = (red[0] + red[1]) * (1.f/512.f);
  float q = 0.f;
  #pragma unroll
  for (int i = 0; i < 4; ++i){ const float d = v[i]-mean; q += d*d; }
  #pragma unroll
  for (int off = 1; off < 64; off <<= 1) q += __shfl_xor(q, off);
  if ((t & 63) == 0) red[2 + (t >> 6)] = q;
  __syncthreads();
  const float var = (red[2] + red[3]) * (1.f/512.f);
  const float rs = rsqrtf(var + 1e-5f);
  const f32x4 gg = *(const f32x4*)&g[c0];
  const f32x4 bb = *(const f32x4*)&bvec[c0];
  float y[4];
  #pragma unroll
  for (int i = 0; i < 4; ++i) y[i] = (v[i] - mean) * rs * gg[i] + bb[i];
  uint2 o; o.x = cvtpk(y[0], y[1]); o.y = cvtpk(y[2], y[3]);
  *(uint2*)&outb[(size_t)row*DIM + c0] = o;
}

// ---------------------------------------------------------------- fused prep+LN0
__global__ __launch_bounds__(256)
void prep_ln(const float* w0, const float* w1, const float* w2, const float* w3,
             const float* w4, const float* w5, const float* w6, const float* w7,
             const float* __restrict__ mem, const int* __restrict__ mkpm,
             const float* saqb, const float* sakb, const float* savb,
             const float* cakb, const float* cavb,
             u16* __restrict__ wtA, u16* __restrict__ memb,
             float* __restrict__ bias, float* __restrict__ bc0,
             float* __restrict__ bc1,
             const float* __restrict__ tgt, const float* __restrict__ pos,
             const float* __restrict__ tkpm,
             const float* __restrict__ n1g, const float* __restrict__ n1b,
             float* __restrict__ xres, u16* __restrict__ t2n)
{
  __shared__ float tile[32][33];
  __shared__ float red8[8];
  const int id = blockIdx.x;
  const int tid = threadIdx.x;
  if (id < 2048){
    const int z = id >> 8, rem = id & 255;
    const int r0 = (rem >> 4) * 32, c0 = (rem & 15) * 32;
    const float* wp[8] = {w0,w1,w2,w3,w4,w5,w6,w7};
    const float* w = wp[z];
    u16* o = wtA + (size_t)z * 512 * 512;
    const int tx = tid & 31, ty = tid >> 5;
    #pragma unroll
    for (int i = 0; i < 4; ++i)
      tile[ty + i*8][tx] = w[(size_t)(r0 + ty + i*8)*512 + c0 + tx];
    __syncthreads();
    #pragma unroll
    for (int i = 0; i < 4; ++i)
      o[(size_t)(c0 + ty + i*8)*512 + r0 + tx] = f2b(tile[tx][ty + i*8]);
  } else if (id < 4096){
    const int i = (id - 2048)*1024 + tid*4;
    f32x4 v = *(const f32x4*)&mem[i];
    uint2 p; p.x = cvtpk(v[0], v[1]); p.y = cvtpk(v[2], v[3]);
    *(uint2*)&memb[i] = p;
  } else if (id < 4112){
    const int j = (id - 4096)*256 + tid;   // 0..4095
    bias[j] = mkpm[j] ? 0.f : -1e30f;
    if (j < 1536) bc0[j] = (j < 512) ? saqb[j] : (j < 1024) ? sakb[j-512] : savb[j-1024];
    if (j < 1024) bc1[j] = (j < 512) ? cakb[j] : cavb[j-512];
  } else {
    // LayerNorm 0: x = tgt+pos -> xres; t2n = (LN(x)*g+b)*tkpm[row]
    const int row = id - 4112;
    const int c0 = tid * 2;
    const float2 tg = *(const float2*)&tgt[(size_t)row*DIM + c0];
    const float2 pp = *(const float2*)&pos[(size_t)row*DIM + c0];
    float v[2] = {tg.x + pp.x, tg.y + pp.y};
    *(float2*)&xres[(size_t)row*DIM + c0] = make_float2(v[0], v[1]);
    float s = v[0] + v[1];
    #pragma unroll
    for (int off = 1; off < 64; off <<= 1) s += __shfl_xor(s, off);
    if ((tid & 63) == 0) red8[tid >> 6] = s;
    __syncthreads();
    const float mean = (red8[0] + red8[1] + red8[2] + red8[3]) * (1.f/512.f);
    float q = 0.f;
    #pragma unroll
    for (int i = 0; i < 2; ++i){ const float d = v[i]-mean; q += d*d; }
    #pragma unroll
    for (int off = 1; off < 64; off <<= 1) q += __shfl_xor(q, off);
    if ((tid & 63) == 0) red8[4 + (tid >> 6)] = q;
    __syncthreads();
    const float var = (red8[4] + red8[5] + red8[6] + red8[7]) * (1.f/512.f);
    const float rs = rsqrtf(var + 1e-5f);
    const float tk = tkpm[row];
    const float2 gg = *(const float2*)&n1g[c0];
    const float2 bb = *(const float2*)&n1b[c0];
    const float y0 = ((v[0] - mean) * rs * gg.x + bb.x) * tk;
    const float y1 = ((v[1] - mean) * rs * gg.y + bb.y) * tk;
    *(u32*)&t2n[(size_t)row*DIM + c0] = cvtpk(y0, y1);
  }
}

// V [b][kv][512] -> Vth [b][h][dh][kv'] with PV K-slot permutation AND
// bank XOR-swizzle folded into the kv index. (standalone, self-attn side)
__global__ __launch_bounds__(256)
void transpose_vperm(const u16* __restrict__ in, u16* __restrict__ out)
{
  __shared__ u16 tile[32][33];
  in  += (size_t)blockIdx.z * KLn * DIM;
  out += (size_t)blockIdx.z * NH * DH * KLn;
  const int tx = threadIdx.x, ty = threadIdx.y;
  const int r0 = blockIdx.y*32, c0 = blockIdx.x*32;   // r=kv, c=dcol
  #pragma unroll
  for (int i = 0; i < 4; ++i)
    tile[ty + i*8][tx] = in[(size_t)(r0 + ty + i*8)*DIM + c0 + tx];
  __syncthreads();
  const int kv = r0 + tx;
  const int s  = (kv & ~31) | (((kv>>2)&3)<<3) | (((kv>>4)&1)<<2) | (kv&3);
  #pragma unroll
  for (int i = 0; i < 4; ++i){
    const int dcol = c0 + ty + i*8;
    const int hh = dcol >> 6, dh = dcol & 63;
    const int kvpos = (s & ~63) | (((((s>>3)&7) ^ (dh&7)) << 3)) | (s & 7);
    out[((size_t)(hh*DH + dh))*KLn + kvpos] = tile[tx][ty + i*8];
  }
}

// Cross-side fused: V perm-transpose (blocks 0..2047) + l1w^T (2048..3071)
// + l2w^T (3072..4095).
__global__ __launch_bounds__(256)
void prep_cross(const u16* __restrict__ vb, u16* __restrict__ vt,
                const float* __restrict__ l1w, u16* __restrict__ l1wt,
                const float* __restrict__ l2w, u16* __restrict__ l2wt)
{
  const int id = blockIdx.x;
  const int tid = threadIdx.x;
  const int tx = tid & 31, ty = tid >> 5;
  if (id < 2048){
    __shared__ u16 tileu[32][33];
    const int z = id >> 10, rem = id & 1023;
    const int c0 = (rem & 15) * 32, r0 = (rem >> 4) * 32;
    const u16* in = vb + (size_t)z * KLn * DIM;
    u16* out = vt + (size_t)z * NH * DH * KLn;
    #pragma unroll
    for (int i = 0; i < 4; ++i)
      tileu[ty + i*8][tx] = in[(size_t)(r0 + ty + i*8)*DIM + c0 + tx];
    __syncthreads();
    const int kv = r0 + tx;
    const int s  = (kv & ~31) | (((kv>>2)&3)<<3) | (((kv>>4)&1)<<2) | (kv&3);
    #pragma unroll
    for (int i = 0; i < 4; ++i){
      const int dcol = c0 + ty + i*8;
      const int hh = dcol >> 6, dh = dcol & 63;
      const int kvpos = (s & ~63) | (((((s>>3)&7) ^ (dh&7)) << 3)) | (s & 7);
      out[((size_t)(hh*DH + dh))*KLn + kvpos] = tileu[tx][ty + i*8];
    }
  } else {
    __shared__ float tilef[32][33];
    if (id < 3072){
      const int rem = id - 2048;
      const int c0 = (rem & 63) * 32, r0 = (rem >> 6) * 32;
      #pragma unroll
      for (int i = 0; i < 4; ++i)
        tilef[ty + i*8][tx] = l1w[(size_t)(r0 + ty + i*8)*FFD + c0 + tx];
      __syncthreads();
      #pragma unroll
      for (int i = 0; i < 4; ++i)
        l1wt[(size_t)(c0 + ty + i*8)*512 + r0 + tx] = f2b(tilef[tx][ty + i*8]);
    } else {
      const int rem = id - 3072;
      const int c0 = (rem & 15) * 32, r0 = (rem >> 4) * 32;
      #pragma unroll
      for (int i = 0; i < 4; ++i)
        tilef[ty + i*8][tx] = l2w[(size_t)(r0 + ty + i*8)*512 + c0 + tx];
      __syncthreads();
      #pragma unroll
      for (int i = 0; i < 4; ++i)
        l2wt[(size_t)(c0 + ty + i*8)*FFD + r0 + tx] = f2b(tilef[tx][ty + i*8]);
    }
  }
}

// ---------------------------------------------------------------- launch
extern "C" void kernel_launch(void* const* d_in, const int* in_sizes, int n_in,
                              void* d_out, int out_size, void* d_ws, size_t ws_size,
                              hipStream_t stream)
{
  const float* tgt  = (const float*)d_in[1];
  const float* mem  = (const float*)d_in[2];
  const float* pos  = (const float*)d_in[3];
  const float* tkpm = (const float*)d_in[5];
  const int*   mkpm = (const int*)d_in[6];
  const float* saqw = (const float*)d_in[7];  const float* saqb = (const float*)d_in[8];
  const float* sakw = (const float*)d_in[9];  const float* sakb = (const float*)d_in[10];
  const float* savw = (const float*)d_in[11]; const float* savb = (const float*)d_in[12];
  const float* saow = (const float*)d_in[13]; const float* saob = (const float*)d_in[14];
  const float* caqw = (const float*)d_in[15]; const float* caqb = (const float*)d_in[16];
  const float* cakw = (const float*)d_in[17]; const float* cakb = (const float*)d_in[18];
  const float* cavw = (const float*)d_in[19]; const float* cavb = (const float*)d_in[20];
  const float* caow = (const float*)d_in[21]; const float* caob = (const float*)d_in[22];
  const float* l1w  = (const float*)d_in[23]; const float* l1b  = (const float*)d_in[24];
  const float* l2w  = (const float*)d_in[25]; const float* l2b  = (const float*)d_in[26];
  const float* n1g  = (const float*)d_in[27]; const float* n1b  = (const float*)d_in[28];
  const float* n2g  = (const float*)d_in[29]; const float* n2b  = (const float*)d_in[30];
  const float* n3g  = (const float*)d_in[31]; const float* n3b  = (const float*)d_in[32];

  if (ws_size < 58720256) return;  // 56 MB scratch

  char* ws = (char*)d_ws;
  float* xres = (float*)(ws);
  u16* t2n    = (u16*)(ws + (8u<<20));
  u16* qb     = (u16*)(ws + (12u<<20));
  u16* kb     = (u16*)(ws + (16u<<20));
  u16* vb     = (u16*)(ws + (20u<<20));
  u16* vt     = (u16*)(ws + (24u<<20));
  float* bias = (float*)(ws + (28u<<20));              // 16 KB
  float* bc0  = (float*)(ws + (28u<<20) + 16384);      // 6 KB
  float* bc1  = (float*)(ws + (28u<<20) + 24576);      // 4 KB
  float2* mlb = (float2*)(ws + (28u<<20) + 32768);     // 512 KB
  u16* l1wt   = (u16*)(ws + (29u<<20));
  u16* l2wt   = (u16*)(ws + (31u<<20));
  u16* memb   = (u16*)(ws + (33u<<20));
  u16* wtA    = (u16*)(ws + (37u<<20));
  u16* ctxp   = (u16*)(ws + (41u<<20));
  u16* ffh    = (u16*)(ws + (12u<<20));   // aliases qb..vt (dead by FF phase)

  float* out = (float*)d_out;
  const int W55 = 512*512;

  prep_ln<<<dim3(8208), 256, 0, stream>>>(saqw, sakw, savw, saow,
                                          caqw, cakw, cavw, caow,
                                          mem, mkpm, saqb, sakb, savb, cakb, cavb,
                                          wtA, memb, bias, bc0, bc1,
                                          tgt, pos, tkpm, n1g, n1b, xres, t2n);

  #define G(EP, GX) gemm64<EP><<<dim3(GX,64), 256, 0, stream>>>

  // ---- self attention (fused QKV: N=1536; merge fused into O-proj)
  G(EPI_QKV, 24)(t2n, wtA, bc0, qb, nullptr, nullptr, nullptr, 512, 1536);
  transpose_vperm<<<dim3(DIM/32, KLn/32, NB), dim3(32,8), 0, stream>>>(vb, vt);
  attn8<true><<<dim3(QL/128, NH, NB*2), 256, 0, stream>>>(qb, kb, vt, nullptr, ctxp, mlb);
  gemm_om<<<dim3(8,64), 256, 0, stream>>>(ctxp, mlb, wtA + 3*W55, saob, xres);

  ln_kernel2<<<MROWS, 128, 0, stream>>>(xres, n2g, n2b, t2n);

  // ---- cross attention (Q + KV projections in ONE launch; merge fused into O-proj)
  gemm_cross<<<dim3(24,64), 256, 0, stream>>>(t2n, memb, wtA + 4*W55, wtA + 5*W55,
                                              caqb, bc1, qb, kb);
  prep_cross<<<dim3(4096), 256, 0, stream>>>(vb, vt, l1w, l1wt, l2w, l2wt);
  attn8<false><<<dim3(QL/128, NH, NB*2), 256, 0, stream>>>(qb, kb, vt, bias, ctxp, mlb);
  gemm_om<<<dim3(8,64), 256, 0, stream>>>(ctxp, mlb, wtA + 7*W55, caob, xres);

  ln_kernel2<<<MROWS, 128, 0, stream>>>(xres, n3g, n3b, t2n);

  // ---- feed-forward (FF2 epilogue fuses residual add + tkpm scale + f32 out)
  G(EPI_RELU, 32)(t2n, l1wt, l1b, ffh, nullptr, nullptr, nullptr, 512, FFD);
  G(EPI_FIN, 8)(ffh, l2wt, l2b, nullptr, xres, tkpm, out, 2048, 512);

  #undef G
}